// Round 4
// baseline (932.720 us; speedup 1.0000x reference)
//
#include <hip/hip_runtime.h>
#include <hip/hip_bf16.h>

// Problem constants (from reference)
#define NN 50000      // nodes
#define NE 800000     // edges
#define NS 2          // samples
#define DIN 128
#define DNOISE 64
#define DH0 192       // DIN + DNOISE
#define DOUT 256      // D0 == D1

typedef __bf16 bf16x8 __attribute__((ext_vector_type(8)));
typedef float floatx4 __attribute__((ext_vector_type(4)));

// ---------------- bf16 helpers (uint = packed bf16 pair, elem 2c in low bits) ----------------

__device__ inline float bflo(unsigned int u) { return __uint_as_float(u << 16); }
__device__ inline float bfhi(unsigned int u) { return __uint_as_float(u & 0xffff0000u); }
__device__ inline unsigned short f2bf_bits(float x) {
    __hip_bfloat16 b = __float2bfloat16(x);
    return *reinterpret_cast<unsigned short*>(&b);
}
__device__ inline unsigned int pack2(float lo, float hi) {
    return (unsigned int)f2bf_bits(lo) | ((unsigned int)f2bf_bits(hi) << 16);
}

// ---------------- CSR build ----------------

__global__ void count_kernel(const int* __restrict__ dst, int* __restrict__ cnt) {
    int i = blockIdx.x * blockDim.x + threadIdx.x;
    if (i < NE) atomicAdd(&cnt[dst[i]], 1);
}

// 4 elements/thread block scan, 13 outer iterations over 50000 counts.
__global__ __launch_bounds__(1024) void scan_kernel(int* __restrict__ cnt /* in: counts, out: write cursor */,
                                                    int* __restrict__ row_ptr) {
    __shared__ int buf[1024];
    __shared__ int carry_s;
    int tid = threadIdx.x;
    if (tid == 0) { carry_s = 0; row_ptr[0] = 0; }
    __syncthreads();
    for (int base = 0; base < NN; base += 4096) {
        int i = base + tid * 4;
        int v0 = 0, v1 = 0, v2 = 0, v3 = 0;
        if (i + 3 < NN) {
            int4 q = *reinterpret_cast<const int4*>(cnt + i);
            v0 = q.x; v1 = q.y; v2 = q.z; v3 = q.w;
        } else {
            if (i < NN) v0 = cnt[i];
            if (i + 1 < NN) v1 = cnt[i + 1];
            if (i + 2 < NN) v2 = cnt[i + 2];
            if (i + 3 < NN) v3 = cnt[i + 3];
        }
        int s = v0 + v1 + v2 + v3;
        buf[tid] = s;
        __syncthreads();
        for (int off = 1; off < 1024; off <<= 1) {
            int t = (tid >= off) ? buf[tid - off] : 0;
            __syncthreads();
            buf[tid] += t;
            __syncthreads();
        }
        int excl = buf[tid] - s + carry_s;
        int p1 = excl + v0, p2 = p1 + v1, p3 = p2 + v2, p4 = p3 + v3;
        if (i < NN)     { cnt[i] = excl;     row_ptr[i + 1] = p1; }
        if (i + 1 < NN) { cnt[i + 1] = p1;   row_ptr[i + 2] = p2; }
        if (i + 2 < NN) { cnt[i + 2] = p2;   row_ptr[i + 3] = p3; }
        if (i + 3 < NN) { cnt[i + 3] = p3;   row_ptr[i + 4] = p4; }
        __syncthreads();
        if (tid == 1023) carry_s = excl + s;
        __syncthreads();
    }
}

__global__ void fill_kernel(const int* __restrict__ src, const int* __restrict__ dst,
                            int* __restrict__ cursor, int* __restrict__ col_idx) {
    int i = blockIdx.x * blockDim.x + threadIdx.x;
    if (i < NE) {
        int p = atomicAdd(&cursor[dst[i]], 1);
        col_idx[p] = src[i];
    }
}

// ---------------- fp32 -> bf16 conversion (4 elems/thread) ----------------

__global__ void tobf16_kernel(const float* __restrict__ src, unsigned short* __restrict__ dst, int n4) {
    int i = blockIdx.x * blockDim.x + threadIdx.x;
    if (i < n4) {
        float4 v = reinterpret_cast<const float4*>(src)[i];
        ushort4 o;
        o.x = f2bf_bits(v.x); o.y = f2bf_bits(v.y); o.z = f2bf_bits(v.z); o.w = f2bf_bits(v.w);
        reinterpret_cast<ushort4*>(dst)[i] = o;
    }
}

// ---------------- W transpose + fp32->bf16 (K x 256 -> 256 x K) ----------------

__global__ void transpose_w(const float* __restrict__ W, __hip_bfloat16* __restrict__ Wt, int K) {
    int n = blockIdx.x;
    for (int k = threadIdx.x; k < K; k += blockDim.x)
        Wt[(size_t)n * K + k] = __float2bfloat16(W[(size_t)k * DOUT + n]);
}

// ---------------- Fused layer 0: agg(X,noise) -> LDS tile -> GEMM -> h1 ----------------
// Block: 32 nodes x 2 samples = 64 M-rows. LDS tile row = 200 bf16 (100 uints,
// 96 data + 4 pad -> 400B stride, bank step 4 -> 2-way conflict = free).
// Agg: 2 nodes/iter; tid>>7 = node slot, cc=tid&127: cc<64 X-uints (written to
// both sample rows, dedup), cc in [64,96) noise s=0, [96,128) noise s=1.
// GEMM: wave w = 16 rows x 256 cols, K=192, B from L2-resident Wt0.

__global__ __launch_bounds__(256) void fused0_kernel(
    const unsigned int* __restrict__ Xb,   // [NN][64] packed bf16 pairs
    const unsigned int* __restrict__ Nb,   // [NS][NN][32]
    const int* __restrict__ row_ptr, const int* __restrict__ col_idx,
    const float* __restrict__ eps0p,
    const __hip_bfloat16* __restrict__ Wt0, // [256][192]
    const float* __restrict__ b0,
    __hip_bfloat16* __restrict__ h1) {      // [NS*NN][256]
    __shared__ unsigned int tile[64][100];
    const int d0 = blockIdx.x * 32;
    const int nodes = min(32, NN - d0);
    const int tid = threadIdx.x;
    const float c = 1.f + eps0p[0];

    if (nodes < 32 && tid < 100) {  // zero invalid rows so GEMM reads no NaN garbage
        for (int r = nodes; r < 32; ++r) { tile[r][tid] = 0; tile[32 + r][tid] = 0; }
    }

    const int j = tid >> 7;      // node slot within pair
    const int cc = tid & 127;
    for (int it = 0; it < 16; ++it) {
        int i = it * 2 + j;
        if (i < nodes) {
            int d = d0 + i;
            int beg = row_ptr[d], end = row_ptr[d + 1];
            if (cc < 64) {
                const unsigned int* src = Xb + cc;
                unsigned int u = src[(size_t)d * 64];
                float aL = c * bflo(u), aH = c * bfhi(u);
                int e = beg;
                for (; e + 3 < end; e += 4) {
                    int i0 = col_idx[e], i1 = col_idx[e + 1], i2 = col_idx[e + 2], i3 = col_idx[e + 3];
                    unsigned int u0 = src[(size_t)i0 * 64], u1 = src[(size_t)i1 * 64];
                    unsigned int u2 = src[(size_t)i2 * 64], u3 = src[(size_t)i3 * 64];
                    aL += (bflo(u0) + bflo(u1)) + (bflo(u2) + bflo(u3));
                    aH += (bfhi(u0) + bfhi(u1)) + (bfhi(u2) + bfhi(u3));
                }
                for (; e < end; ++e) {
                    unsigned int ue = src[(size_t)col_idx[e] * 64];
                    aL += bflo(ue); aH += bfhi(ue);
                }
                unsigned int r = pack2(aL, aH);
                tile[i][cc] = r;          // sample 0
                tile[32 + i][cc] = r;     // sample 1 (X part is sample-independent)
            } else {
                int s = (cc - 64) >> 5, col = (cc - 64) & 31;
                const unsigned int* src = Nb + (size_t)s * NN * 32 + col;
                unsigned int u = src[(size_t)d * 32];
                float aL = c * bflo(u), aH = c * bfhi(u);
                int e = beg;
                for (; e + 3 < end; e += 4) {
                    int i0 = col_idx[e], i1 = col_idx[e + 1], i2 = col_idx[e + 2], i3 = col_idx[e + 3];
                    unsigned int u0 = src[(size_t)i0 * 32], u1 = src[(size_t)i1 * 32];
                    unsigned int u2 = src[(size_t)i2 * 32], u3 = src[(size_t)i3 * 32];
                    aL += (bflo(u0) + bflo(u1)) + (bflo(u2) + bflo(u3));
                    aH += (bfhi(u0) + bfhi(u1)) + (bfhi(u2) + bfhi(u3));
                }
                for (; e < end; ++e) {
                    unsigned int ue = src[(size_t)col_idx[e] * 32];
                    aL += bflo(ue); aH += bfhi(ue);
                }
                tile[s * 32 + i][64 + col] = pack2(aL, aH);
            }
        }
    }
    __syncthreads();

    // GEMM phase. Layouts (m89/m120-verified): A[m=lane&15][k=quad*8+j];
    // B[k=quad*8+j][n=lane&15]; D: col=lane&15, row=quad*4+reg.
    const int lane = tid & 63, w = tid >> 6;
    const int lo = lane & 15, quad = lane >> 4;
    floatx4 acc[16];
#pragma unroll
    for (int t = 0; t < 16; ++t) acc[t] = (floatx4){0.f, 0.f, 0.f, 0.f};
    const unsigned int* arow = &tile[w * 16 + lo][0];
    for (int k0 = 0; k0 < DH0; k0 += 32) {
        bf16x8 a = *reinterpret_cast<const bf16x8*>(arow + k0 / 2 + quad * 4);
#pragma unroll
        for (int t = 0; t < 16; ++t) {
            bf16x8 b = *reinterpret_cast<const bf16x8*>(Wt0 + (size_t)(t * 16 + lo) * DH0 + k0 + quad * 8);
            acc[t] = __builtin_amdgcn_mfma_f32_16x16x32_bf16(a, b, acc[t], 0, 0, 0);
        }
    }
#pragma unroll
    for (int t = 0; t < 16; ++t) {
        int col = t * 16 + lo;
        float bv = b0[col];
#pragma unroll
        for (int r = 0; r < 4; ++r) {
            int lr = w * 16 + quad * 4 + r;
            int i = lr & 31, s = lr >> 5;
            if (i < nodes) {
                float v = acc[t][r] + bv;
                h1[(size_t)(s * NN + d0 + i) * DOUT + col] = __float2bfloat16(v > 0.f ? v : 0.f);
            }
        }
    }
}

// ---------------- Fused layer 1: agg(h1) -> LDS tile -> GEMM -> out (fp32) ----------------
// LDS row = 264 bf16 (132 uints, 128 data + 4 pad -> 528B stride, bank step 4).

__global__ __launch_bounds__(256) void fused1_kernel(
    const unsigned int* __restrict__ h,    // [NS*NN][128] packed bf16 pairs
    const int* __restrict__ row_ptr, const int* __restrict__ col_idx,
    const float* __restrict__ eps1p,
    const __hip_bfloat16* __restrict__ Wt1, // [256][256]
    const float* __restrict__ b1,
    float* __restrict__ out) {              // [NS*NN][256]
    __shared__ unsigned int tile[64][132];
    const int d0 = blockIdx.x * 32;
    const int nodes = min(32, NN - d0);
    const int tid = threadIdx.x;
    const float c = 1.f + eps1p[0];

    if (nodes < 32 && tid < 132) {
        for (int r = nodes; r < 32; ++r) { tile[r][tid] = 0; tile[32 + r][tid] = 0; }
    }

    const int s = tid >> 7, cc = tid & 127;
    const unsigned int* src = h + (size_t)s * NN * 128 + cc;
    for (int i = 0; i < nodes; ++i) {
        int d = d0 + i;
        int beg = row_ptr[d], end = row_ptr[d + 1];
        unsigned int u = src[(size_t)d * 128];
        float aL = c * bflo(u), aH = c * bfhi(u);
        int e = beg;
        for (; e + 3 < end; e += 4) {
            int i0 = col_idx[e], i1 = col_idx[e + 1], i2 = col_idx[e + 2], i3 = col_idx[e + 3];
            unsigned int u0 = src[(size_t)i0 * 128], u1 = src[(size_t)i1 * 128];
            unsigned int u2 = src[(size_t)i2 * 128], u3 = src[(size_t)i3 * 128];
            aL += (bflo(u0) + bflo(u1)) + (bflo(u2) + bflo(u3));
            aH += (bfhi(u0) + bfhi(u1)) + (bfhi(u2) + bfhi(u3));
        }
        for (; e < end; ++e) {
            unsigned int ue = src[(size_t)col_idx[e] * 128];
            aL += bflo(ue); aH += bfhi(ue);
        }
        tile[s * 32 + i][cc] = pack2(aL, aH);
    }
    __syncthreads();

    const int lane = tid & 63, w = tid >> 6;
    const int lo = lane & 15, quad = lane >> 4;
    floatx4 acc[16];
#pragma unroll
    for (int t = 0; t < 16; ++t) acc[t] = (floatx4){0.f, 0.f, 0.f, 0.f};
    const unsigned int* arow = &tile[w * 16 + lo][0];
    for (int k0 = 0; k0 < DOUT; k0 += 32) {
        bf16x8 a = *reinterpret_cast<const bf16x8*>(arow + k0 / 2 + quad * 4);
#pragma unroll
        for (int t = 0; t < 16; ++t) {
            bf16x8 b = *reinterpret_cast<const bf16x8*>(Wt1 + (size_t)(t * 16 + lo) * DOUT + k0 + quad * 8);
            acc[t] = __builtin_amdgcn_mfma_f32_16x16x32_bf16(a, b, acc[t], 0, 0, 0);
        }
    }
#pragma unroll
    for (int t = 0; t < 16; ++t) {
        int col = t * 16 + lo;
        float bv = b1[col];
#pragma unroll
        for (int r = 0; r < 4; ++r) {
            int lr = w * 16 + quad * 4 + r;
            int i = lr & 31, sp = lr >> 5;
            if (i < nodes) {
                float v = acc[t][r] + bv;
                out[(size_t)(sp * NN + d0 + i) * DOUT + col] = v > 0.f ? v : 0.f;
            }
        }
    }
}

// ---------------- epsilon passthrough (output 1, fp32) ----------------

__global__ void copy_eps(const uint4* __restrict__ src, uint4* __restrict__ dst) {
    int i = blockIdx.x * blockDim.x + threadIdx.x;
    const int n16 = (NS * NN * DNOISE * 4) / 16;
    if (i < n16) dst[i] = src[i];
}

extern "C" void kernel_launch(void* const* d_in, const int* in_sizes, int n_in,
                              void* d_out, int out_size, void* d_ws, size_t ws_size,
                              hipStream_t stream) {
    const float* X = (const float*)d_in[0];
    const float* noise = (const float*)d_in[1];
    const int* esrc = (const int*)d_in[2];
    const int* edst = (const int*)d_in[3];
    const float* W0 = (const float*)d_in[4];
    const float* b0 = (const float*)d_in[5];
    const float* W1 = (const float*)d_in[6];
    const float* b1 = (const float*)d_in[7];
    const float* eps0 = (const float*)d_in[8];
    const float* eps1 = (const float*)d_in[9];
    float* out = (float*)d_out;

    const int M = NS * NN;  // 100000

    // Workspace carve (~55 MB, same footprint as R3 which fit).
    char* w = (char*)d_ws;
    auto carve = [&](size_t bytes) { char* p = w; w += (bytes + 511) & ~(size_t)511; return p; };
    int* cursor = (int*)carve((size_t)NN * 4);
    int* row_ptr = (int*)carve((size_t)(NN + 1) * 4);
    int* col_idx = (int*)carve((size_t)NE * 4);
    __hip_bfloat16* Wt0 = (__hip_bfloat16*)carve((size_t)DH0 * DOUT * 2);
    __hip_bfloat16* Wt1 = (__hip_bfloat16*)carve((size_t)DOUT * DOUT * 2);
    __hip_bfloat16* h1 = (__hip_bfloat16*)carve((size_t)M * DOUT * 2);  // 51.2 MB

    // bf16 copies of X and noise live in the epsilon region of d_out (25.6 MB);
    // consumed only by fused0, overwritten by copy_eps at the very end.
    unsigned short* Xb = (unsigned short*)(out + (size_t)M * DOUT);         // 12.8 MB
    unsigned short* Nb = Xb + (size_t)NN * DIN;                             // 12.8 MB

    hipMemsetAsync(cursor, 0, (size_t)NN * 4, stream);
    count_kernel<<<(NE + 255) / 256, 256, 0, stream>>>(edst, cursor);
    scan_kernel<<<1, 1024, 0, stream>>>(cursor, row_ptr);
    fill_kernel<<<(NE + 255) / 256, 256, 0, stream>>>(esrc, edst, cursor, col_idx);
    tobf16_kernel<<<(NN * DIN / 4 + 255) / 256, 256, 0, stream>>>(X, Xb, NN * DIN / 4);
    tobf16_kernel<<<(NS * NN * DNOISE / 4 + 255) / 256, 256, 0, stream>>>(noise, Nb, NS * NN * DNOISE / 4);
    transpose_w<<<DOUT, 256, 0, stream>>>(W0, Wt0, DH0);
    transpose_w<<<DOUT, 256, 0, stream>>>(W1, Wt1, DOUT);

    const int nblocks = (NN + 31) / 32;  // 1563
    fused0_kernel<<<nblocks, 256, 0, stream>>>(
        (const unsigned int*)Xb, (const unsigned int*)Nb, row_ptr, col_idx, eps0, Wt0, b0, h1);
    fused1_kernel<<<nblocks, 256, 0, stream>>>(
        (const unsigned int*)h1, row_ptr, col_idx, eps1, Wt1, b1, out);

    copy_eps<<<((NS * NN * DNOISE * 4 / 16) + 255) / 256, 256, 0, stream>>>(
        (const uint4*)noise, (uint4*)(out + (size_t)M * DOUT));
}

// Round 5
// 620.831 us; speedup vs baseline: 1.5024x; 1.5024x over previous
//
#include <hip/hip_runtime.h>
#include <hip/hip_bf16.h>

// Problem constants (from reference)
#define NN 50000      // nodes
#define NE 800000     // edges
#define NS 2          // samples
#define DIN 128
#define DNOISE 64
#define DH0 192       // DIN + DNOISE
#define DOUT 256      // D0 == D1

typedef __bf16 bf16x8 __attribute__((ext_vector_type(8)));
typedef float floatx4 __attribute__((ext_vector_type(4)));

// ---------------- bf16 helpers (uint = packed bf16 pair) ----------------

__device__ inline float bflo(unsigned int u) { return __uint_as_float(u << 16); }
__device__ inline float bfhi(unsigned int u) { return __uint_as_float(u & 0xffff0000u); }
__device__ inline unsigned short f2bf_bits(float x) {
    __hip_bfloat16 b = __float2bfloat16(x);
    return *reinterpret_cast<unsigned short*>(&b);
}
__device__ inline unsigned int pack2(float lo, float hi) {
    return (unsigned int)f2bf_bits(lo) | ((unsigned int)f2bf_bits(hi) << 16);
}

// ---------------- CSR build ----------------

__global__ void count_kernel(const int* __restrict__ dst, int* __restrict__ cnt) {
    int i = blockIdx.x * blockDim.x + threadIdx.x;
    if (i < NE) atomicAdd(&cnt[dst[i]], 1);
}

// 4 elements/thread block scan, 13 outer iterations over 50000 counts.
__global__ __launch_bounds__(1024) void scan_kernel(int* __restrict__ cnt /* in: counts, out: write cursor */,
                                                    int* __restrict__ row_ptr) {
    __shared__ int buf[1024];
    __shared__ int carry_s;
    int tid = threadIdx.x;
    if (tid == 0) { carry_s = 0; row_ptr[0] = 0; }
    __syncthreads();
    for (int base = 0; base < NN; base += 4096) {
        int i = base + tid * 4;
        int v0 = 0, v1 = 0, v2 = 0, v3 = 0;
        if (i + 3 < NN) {
            int4 q = *reinterpret_cast<const int4*>(cnt + i);
            v0 = q.x; v1 = q.y; v2 = q.z; v3 = q.w;
        } else {
            if (i < NN) v0 = cnt[i];
            if (i + 1 < NN) v1 = cnt[i + 1];
            if (i + 2 < NN) v2 = cnt[i + 2];
            if (i + 3 < NN) v3 = cnt[i + 3];
        }
        int s = v0 + v1 + v2 + v3;
        buf[tid] = s;
        __syncthreads();
        for (int off = 1; off < 1024; off <<= 1) {
            int t = (tid >= off) ? buf[tid - off] : 0;
            __syncthreads();
            buf[tid] += t;
            __syncthreads();
        }
        int excl = buf[tid] - s + carry_s;
        int p1 = excl + v0, p2 = p1 + v1, p3 = p2 + v2, p4 = p3 + v3;
        if (i < NN)     { cnt[i] = excl;     row_ptr[i + 1] = p1; }
        if (i + 1 < NN) { cnt[i + 1] = p1;   row_ptr[i + 2] = p2; }
        if (i + 2 < NN) { cnt[i + 2] = p2;   row_ptr[i + 3] = p3; }
        if (i + 3 < NN) { cnt[i + 3] = p3;   row_ptr[i + 4] = p4; }
        __syncthreads();
        if (tid == 1023) carry_s = excl + s;
        __syncthreads();
    }
}

__global__ void fill_kernel(const int* __restrict__ src, const int* __restrict__ dst,
                            int* __restrict__ cursor, int* __restrict__ col_idx) {
    int i = blockIdx.x * blockDim.x + threadIdx.x;
    if (i < NE) {
        int p = atomicAdd(&cursor[dst[i]], 1);
        col_idx[p] = src[i];
    }
}

// ---------------- fp32 -> bf16 conversion (4 elems/thread) ----------------

__global__ void tobf16_kernel(const float* __restrict__ src, unsigned short* __restrict__ dst, int n4) {
    int i = blockIdx.x * blockDim.x + threadIdx.x;
    if (i < n4) {
        float4 v = reinterpret_cast<const float4*>(src)[i];
        ushort4 o;
        o.x = f2bf_bits(v.x); o.y = f2bf_bits(v.y); o.z = f2bf_bits(v.z); o.w = f2bf_bits(v.w);
        reinterpret_cast<ushort4*>(dst)[i] = o;
    }
}

// ---------------- W transpose + fp32->bf16 (K x 256 -> 256 x K) ----------------

__global__ void transpose_w(const float* __restrict__ W, __hip_bfloat16* __restrict__ Wt, int K) {
    int n = blockIdx.x;
    for (int k = threadIdx.x; k < K; k += blockDim.x)
        Wt[(size_t)n * K + k] = __float2bfloat16(W[(size_t)k * DOUT + n]);
}

// ---------------- Layer 0 aggregation (bf16 gather, X deduped across samples) ----------------
// 2 nodes/block (slot j = tid>>7), 128 threads/node: cc<64 X-uints (written to
// both samples), cc in [64,96) noise s=0, [96,128) noise s=1. x4-unrolled edge
// loop = 4 concurrent gathers/thread. Grid 25000 blocks -> huge gather concurrency.

__global__ __launch_bounds__(256) void agg0_kernel(
    const unsigned int* __restrict__ Xb,   // [NN][64] packed bf16 pairs
    const unsigned int* __restrict__ Nb,   // [NS][NN][32]
    const int* __restrict__ row_ptr, const int* __restrict__ col_idx,
    const float* __restrict__ eps0p,
    unsigned int* __restrict__ z0) {       // [NS*NN][96]
    const int d = blockIdx.x * 2 + (threadIdx.x >> 7);
    const int cc = threadIdx.x & 127;
    const float c = 1.f + eps0p[0];
    const int beg = row_ptr[d], end = row_ptr[d + 1];
    if (cc < 64) {
        const unsigned int* src = Xb + cc;
        unsigned int u = src[(size_t)d * 64];
        float aL = c * bflo(u), aH = c * bfhi(u);
        int e = beg;
        for (; e + 3 < end; e += 4) {
            int i0 = col_idx[e], i1 = col_idx[e + 1], i2 = col_idx[e + 2], i3 = col_idx[e + 3];
            unsigned int u0 = src[(size_t)i0 * 64], u1 = src[(size_t)i1 * 64];
            unsigned int u2 = src[(size_t)i2 * 64], u3 = src[(size_t)i3 * 64];
            aL += (bflo(u0) + bflo(u1)) + (bflo(u2) + bflo(u3));
            aH += (bfhi(u0) + bfhi(u1)) + (bfhi(u2) + bfhi(u3));
        }
        for (; e < end; ++e) {
            unsigned int ue = src[(size_t)col_idx[e] * 64];
            aL += bflo(ue); aH += bfhi(ue);
        }
        unsigned int r = pack2(aL, aH);
        z0[(size_t)d * 96 + cc] = r;             // sample 0
        z0[(size_t)(NN + d) * 96 + cc] = r;      // sample 1 (X part sample-independent)
    } else {
        int s = (cc - 64) >> 5, col = (cc - 64) & 31;
        const unsigned int* src = Nb + (size_t)s * NN * 32 + col;
        unsigned int u = src[(size_t)d * 32];
        float aL = c * bflo(u), aH = c * bfhi(u);
        int e = beg;
        for (; e + 3 < end; e += 4) {
            int i0 = col_idx[e], i1 = col_idx[e + 1], i2 = col_idx[e + 2], i3 = col_idx[e + 3];
            unsigned int u0 = src[(size_t)i0 * 32], u1 = src[(size_t)i1 * 32];
            unsigned int u2 = src[(size_t)i2 * 32], u3 = src[(size_t)i3 * 32];
            aL += (bflo(u0) + bflo(u1)) + (bflo(u2) + bflo(u3));
            aH += (bfhi(u0) + bfhi(u1)) + (bfhi(u2) + bfhi(u3));
        }
        for (; e < end; ++e) {
            unsigned int ue = src[(size_t)col_idx[e] * 32];
            aL += bflo(ue); aH += bfhi(ue);
        }
        z0[(size_t)(s * NN + d) * 96 + 64 + col] = pack2(aL, aH);
    }
}

// ---------------- Layer 1 aggregation (bf16 gather, uint2 loads) ----------------
// 2 nodes/block (slot j = tid>>7), per node 128 threads = 64 cols-of-uint2 x 2
// samples. x4-unrolled edge loop, 8B loads.

__global__ __launch_bounds__(256) void agg1_kernel(
    const uint2* __restrict__ h,           // [NS*NN][64] (uint2 = 4 bf16)
    const int* __restrict__ row_ptr, const int* __restrict__ col_idx,
    const float* __restrict__ eps1p,
    uint2* __restrict__ z1) {              // [NS*NN][64]
    const int d = blockIdx.x * 2 + (threadIdx.x >> 7);
    const int s = (threadIdx.x >> 6) & 1;
    const int cc = threadIdx.x & 63;
    const float c = 1.f + eps1p[0];
    const int beg = row_ptr[d], end = row_ptr[d + 1];
    const uint2* src = h + (size_t)s * NN * 64 + cc;
    uint2 u = src[(size_t)d * 64];
    float aL0 = c * bflo(u.x), aH0 = c * bfhi(u.x);
    float aL1 = c * bflo(u.y), aH1 = c * bfhi(u.y);
    int e = beg;
    for (; e + 3 < end; e += 4) {
        int i0 = col_idx[e], i1 = col_idx[e + 1], i2 = col_idx[e + 2], i3 = col_idx[e + 3];
        uint2 u0 = src[(size_t)i0 * 64], u1 = src[(size_t)i1 * 64];
        uint2 u2 = src[(size_t)i2 * 64], u3 = src[(size_t)i3 * 64];
        aL0 += (bflo(u0.x) + bflo(u1.x)) + (bflo(u2.x) + bflo(u3.x));
        aH0 += (bfhi(u0.x) + bfhi(u1.x)) + (bfhi(u2.x) + bfhi(u3.x));
        aL1 += (bflo(u0.y) + bflo(u1.y)) + (bflo(u2.y) + bflo(u3.y));
        aH1 += (bfhi(u0.y) + bfhi(u1.y)) + (bfhi(u2.y) + bfhi(u3.y));
    }
    for (; e < end; ++e) {
        uint2 ue = src[(size_t)col_idx[e] * 64];
        aL0 += bflo(ue.x); aH0 += bfhi(ue.x);
        aL1 += bflo(ue.y); aH1 += bfhi(ue.y);
    }
    uint2 r; r.x = pack2(aL0, aH0); r.y = pack2(aL1, aH1);
    z1[(size_t)(s * NN + d) * 64 + cc] = r;
}

// ---------------- GEMM: C = relu(A @ W + b), N fixed at 256 ----------------
// A: M x K bf16 row-major; Wt: 256 x K bf16; C: M x 256 (OUT_T).
// Each wave: 32 rows (two 16-row tiles sharing each B fragment) x 256 cols.
// Layouts (m89/m120-verified): A[m=lane&15][k=quad*8+j]; B[k=quad*8+j][n=lane&15];
// D: col=lane&15, row=quad*4+reg.

__device__ inline void store_out(float* C, size_t idx, float v) { C[idx] = v; }
__device__ inline void store_out(__hip_bfloat16* C, size_t idx, float v) { C[idx] = __float2bfloat16(v); }

template <typename OUT_T>
__global__ __launch_bounds__(256) void gemm_bias_relu(
    const __hip_bfloat16* __restrict__ A, const __hip_bfloat16* __restrict__ Wt,
    const float* __restrict__ bias, OUT_T* __restrict__ C,
    int M, int K) {
    const int lane = threadIdx.x & 63;
    const int wave = threadIdx.x >> 6;
    const int rowBase = blockIdx.x * 128 + wave * 32;   // M % 32 == 0
    if (rowBase >= M) return;
    const int lo = lane & 15;
    const int quad = lane >> 4;

    floatx4 acc0[16], acc1[16];
#pragma unroll
    for (int t = 0; t < 16; ++t) {
        acc0[t] = (floatx4){0.f, 0.f, 0.f, 0.f};
        acc1[t] = (floatx4){0.f, 0.f, 0.f, 0.f};
    }

    const __hip_bfloat16* arow0 = A + (size_t)(rowBase + lo) * K + quad * 8;
    const __hip_bfloat16* arow1 = arow0 + (size_t)16 * K;
    for (int k0 = 0; k0 < K; k0 += 32) {
        bf16x8 a0 = *reinterpret_cast<const bf16x8*>(arow0 + k0);
        bf16x8 a1 = *reinterpret_cast<const bf16x8*>(arow1 + k0);
#pragma unroll
        for (int t = 0; t < 16; ++t) {
            bf16x8 b = *reinterpret_cast<const bf16x8*>(Wt + (size_t)(t * 16 + lo) * K + k0 + quad * 8);
            acc0[t] = __builtin_amdgcn_mfma_f32_16x16x32_bf16(a0, b, acc0[t], 0, 0, 0);
            acc1[t] = __builtin_amdgcn_mfma_f32_16x16x32_bf16(a1, b, acc1[t], 0, 0, 0);
        }
    }

#pragma unroll
    for (int t = 0; t < 16; ++t) {
        int col = t * 16 + lo;
        float bv = bias[col];
#pragma unroll
        for (int r = 0; r < 4; ++r) {
            int row0 = rowBase + quad * 4 + r;
            float v0 = acc0[t][r] + bv;
            store_out(C, (size_t)row0 * DOUT + col, v0 > 0.f ? v0 : 0.f);
            float v1 = acc1[t][r] + bv;
            store_out(C, (size_t)(row0 + 16) * DOUT + col, v1 > 0.f ? v1 : 0.f);
        }
    }
}

// ---------------- epsilon passthrough (output 1, fp32) ----------------

__global__ void copy_eps(const uint4* __restrict__ src, uint4* __restrict__ dst) {
    int i = blockIdx.x * blockDim.x + threadIdx.x;
    const int n16 = (NS * NN * DNOISE * 4) / 16;
    if (i < n16) dst[i] = src[i];
}

extern "C" void kernel_launch(void* const* d_in, const int* in_sizes, int n_in,
                              void* d_out, int out_size, void* d_ws, size_t ws_size,
                              hipStream_t stream) {
    const float* X = (const float*)d_in[0];
    const float* noise = (const float*)d_in[1];
    const int* esrc = (const int*)d_in[2];
    const int* edst = (const int*)d_in[3];
    const float* W0 = (const float*)d_in[4];
    const float* b0 = (const float*)d_in[5];
    const float* W1 = (const float*)d_in[6];
    const float* b1 = (const float*)d_in[7];
    const float* eps0 = (const float*)d_in[8];
    const float* eps1 = (const float*)d_in[9];
    float* out = (float*)d_out;

    const int M = NS * NN;  // 100000

    // Workspace carve (~55 MB, R3-proven footprint).
    char* w = (char*)d_ws;
    auto carve = [&](size_t bytes) { char* p = w; w += (bytes + 511) & ~(size_t)511; return p; };
    int* cursor = (int*)carve((size_t)NN * 4);
    int* row_ptr = (int*)carve((size_t)(NN + 1) * 4);
    int* col_idx = (int*)carve((size_t)NE * 4);
    __hip_bfloat16* Wt0 = (__hip_bfloat16*)carve((size_t)DH0 * DOUT * 2);
    __hip_bfloat16* Wt1 = (__hip_bfloat16*)carve((size_t)DOUT * DOUT * 2);
    unsigned int* z = (unsigned int*)carve((size_t)M * DOUT * 2);  // z0 (96 uints/row) then z1 (64 uint2/row)

    // h1 (bf16, 51.2 MB) staged at the start of the fp32 out region (102.4 MB);
    // dead before gemm1 overwrites that region with out.
    __hip_bfloat16* h1 = (__hip_bfloat16*)d_out;
    // bf16 X/noise copies live in the epsilon region (25.6 MB); dead after agg0,
    // overwritten by copy_eps at the very end.
    unsigned short* Xb = (unsigned short*)(out + (size_t)M * DOUT);  // 12.8 MB
    unsigned short* Nb = Xb + (size_t)NN * DIN;                      // 12.8 MB

    hipMemsetAsync(cursor, 0, (size_t)NN * 4, stream);
    count_kernel<<<(NE + 255) / 256, 256, 0, stream>>>(edst, cursor);
    scan_kernel<<<1, 1024, 0, stream>>>(cursor, row_ptr);
    fill_kernel<<<(NE + 255) / 256, 256, 0, stream>>>(esrc, edst, cursor, col_idx);
    tobf16_kernel<<<(NN * DIN / 4 + 255) / 256, 256, 0, stream>>>(X, Xb, NN * DIN / 4);
    tobf16_kernel<<<(NS * NN * DNOISE / 4 + 255) / 256, 256, 0, stream>>>(noise, Nb, NS * NN * DNOISE / 4);
    transpose_w<<<DOUT, 256, 0, stream>>>(W0, Wt0, DH0);
    transpose_w<<<DOUT, 256, 0, stream>>>(W1, Wt1, DOUT);

    agg0_kernel<<<NN / 2, 256, 0, stream>>>(
        (const unsigned int*)Xb, (const unsigned int*)Nb, row_ptr, col_idx, eps0, z);
    gemm_bias_relu<__hip_bfloat16><<<(M + 127) / 128, 256, 0, stream>>>(
        (const __hip_bfloat16*)z, Wt0, b0, h1, M, DH0);
    agg1_kernel<<<NN / 2, 256, 0, stream>>>(
        (const uint2*)h1, row_ptr, col_idx, eps1, (uint2*)z);
    gemm_bias_relu<float><<<(M + 127) / 128, 256, 0, stream>>>(
        (const __hip_bfloat16*)z, Wt1, b1, out, M, DOUT);

    copy_eps<<<((NS * NN * DNOISE * 4 / 16) + 255) / 256, 256, 0, stream>>>(
        (const uint4*)noise, (uint4*)(out + (size_t)M * DOUT));
}

// Round 6
// 611.642 us; speedup vs baseline: 1.5249x; 1.0150x over previous
//
#include <hip/hip_runtime.h>
#include <hip/hip_bf16.h>

// Problem constants (from reference)
#define NN 50000      // nodes
#define NE 800000     // edges
#define NS 2          // samples
#define DIN 128
#define DNOISE 64
#define DH0 192       // DIN + DNOISE
#define DOUT 256      // D0 == D1
#define NB 49         // scan blocks = ceil(NN/1024)

typedef __bf16 bf16x8 __attribute__((ext_vector_type(8)));
typedef float floatx4 __attribute__((ext_vector_type(4)));

// ---------------- bf16 helpers (uint = packed bf16 pair) ----------------

__device__ inline float bflo(unsigned int u) { return __uint_as_float(u << 16); }
__device__ inline float bfhi(unsigned int u) { return __uint_as_float(u & 0xffff0000u); }
__device__ inline unsigned short f2bf_bits(float x) {
    __hip_bfloat16 b = __float2bfloat16(x);
    return *reinterpret_cast<unsigned short*>(&b);
}
__device__ inline unsigned int pack2(float lo, float hi) {
    return (unsigned int)f2bf_bits(lo) | ((unsigned int)f2bf_bits(hi) << 16);
}

// ---------------- CSR build ----------------

__global__ void count_kernel(const int* __restrict__ dst, int* __restrict__ cnt) {
    int i = blockIdx.x * blockDim.x + threadIdx.x;
    if (i < NE) atomicAdd(&cnt[dst[i]], 1);
}

// Phase A: per-block reduce of counts -> bsum[49]
__global__ __launch_bounds__(1024) void scanA_kernel(const int* __restrict__ cnt, int* __restrict__ bsum) {
    int i = blockIdx.x * 1024 + threadIdx.x;
    int v = (i < NN) ? cnt[i] : 0;
    for (int off = 32; off > 0; off >>= 1) v += __shfl_down(v, off);
    __shared__ int wsum[16];
    if ((threadIdx.x & 63) == 0) wsum[threadIdx.x >> 6] = v;
    __syncthreads();
    if (threadIdx.x == 0) {
        int s = 0;
        for (int k = 0; k < 16; ++k) s += wsum[k];
        bsum[blockIdx.x] = s;
    }
}

// Phase B: exclusive scan of 49 block sums (single wave, shfl scan)
__global__ __launch_bounds__(64) void scanB_kernel(int* __restrict__ bsum) {
    int lane = threadIdx.x;
    int orig = (lane < NB) ? bsum[lane] : 0;
    int v = orig;
    for (int off = 1; off < 64; off <<= 1) {
        int t = __shfl_up(v, off);
        if (lane >= off) v += t;
    }
    if (lane < NB) bsum[lane] = v - orig;  // exclusive
}

// Phase C: intra-block scan + block offset -> row_ptr, cursor
__global__ __launch_bounds__(1024) void scanC_kernel(int* __restrict__ cnt, const int* __restrict__ bsum,
                                                     int* __restrict__ row_ptr) {
    __shared__ int buf[1024];
    int tid = threadIdx.x;
    int i = blockIdx.x * 1024 + tid;
    int v = (i < NN) ? cnt[i] : 0;
    buf[tid] = v;
    __syncthreads();
    for (int off = 1; off < 1024; off <<= 1) {
        int t = (tid >= off) ? buf[tid - off] : 0;
        __syncthreads();
        buf[tid] += t;
        __syncthreads();
    }
    int excl = buf[tid] - v + bsum[blockIdx.x];
    if (i < NN) { row_ptr[i + 1] = excl + v; cnt[i] = excl; }  // cnt becomes write cursor
    if (i == 0) row_ptr[0] = 0;
}

__global__ void fill_kernel(const int* __restrict__ src, const int* __restrict__ dst,
                            int* __restrict__ cursor, int* __restrict__ col_idx) {
    int i = blockIdx.x * blockDim.x + threadIdx.x;
    if (i < NE) {
        int p = atomicAdd(&cursor[dst[i]], 1);
        col_idx[p] = src[i];
    }
}

// ---------------- input prep: X fp32->bf16 + noise fp32 -> bitpacked uint2 ----------------
// blocks [0, XB4): X convert (float4 granularity). blocks [XB4, XB4+NR): noise rows.
#define XQ (NN * DIN / 4)          // 1.6M float4 units
#define XB4 ((XQ + 255) / 256)     // 6250
#define NR_BLOCKS ((NS * NN + 255) / 256)  // 391

__global__ void prep_kernel(const float* __restrict__ X, unsigned short* __restrict__ Xb,
                            const float* __restrict__ noise, uint2* __restrict__ Nbit) {
    int b = blockIdx.x;
    if (b < XB4) {
        int i = b * 256 + threadIdx.x;
        if (i < XQ) {
            float4 v = reinterpret_cast<const float4*>(X)[i];
            ushort4 o;
            o.x = f2bf_bits(v.x); o.y = f2bf_bits(v.y); o.z = f2bf_bits(v.z); o.w = f2bf_bits(v.w);
            reinterpret_cast<ushort4*>(Xb)[i] = o;
        }
    } else {
        int r = (b - XB4) * 256 + threadIdx.x;  // (s*NN + node)
        if (r < NS * NN) {
            const float4* p = reinterpret_cast<const float4*>(noise + (size_t)r * DNOISE);
            unsigned int lo = 0, hi = 0;
            for (int q = 0; q < 8; ++q) {
                float4 v = p[q];
                int base = q * 4;
                lo |= (v.x != 0.f ? 1u : 0u) << base;
                lo |= (v.y != 0.f ? 1u : 0u) << (base + 1);
                lo |= (v.z != 0.f ? 1u : 0u) << (base + 2);
                lo |= (v.w != 0.f ? 1u : 0u) << (base + 3);
            }
            for (int q = 8; q < 16; ++q) {
                float4 v = p[q];
                int base = q * 4 - 32;
                hi |= (v.x != 0.f ? 1u : 0u) << base;
                hi |= (v.y != 0.f ? 1u : 0u) << (base + 1);
                hi |= (v.z != 0.f ? 1u : 0u) << (base + 2);
                hi |= (v.w != 0.f ? 1u : 0u) << (base + 3);
            }
            uint2 o; o.x = lo; o.y = hi;
            Nbit[r] = o;
        }
    }
}

// ---------------- W transposes, both layers in one launch ----------------

__global__ void transpose_both(const float* __restrict__ W0, const float* __restrict__ W1,
                               __hip_bfloat16* __restrict__ Wt0, __hip_bfloat16* __restrict__ Wt1) {
    int b = blockIdx.x;
    if (b < DOUT) {
        for (int k = threadIdx.x; k < DH0; k += blockDim.x)
            Wt0[(size_t)b * DH0 + k] = __float2bfloat16(W0[(size_t)k * DOUT + b]);
    } else {
        int n = b - DOUT;
        for (int k = threadIdx.x; k < DOUT; k += blockDim.x)
            Wt1[(size_t)n * DOUT + k] = __float2bfloat16(W1[(size_t)k * DOUT + n]);
    }
}

// ---------------- Layer 0 aggregation ----------------
// 2 nodes/block (slot = tid>>7), 128 threads/node:
//   cc in [0,64): X uints, gathered from Xb, written to BOTH samples (dedup).
//   cc in [64,128): noise via bitpacked table (L2-resident, 800 KB): j=cc-64,
//     s=j>>5, c=j&31 -> dims 2c,2c+1; per edge one broadcast 8B load + bit extract,
//     integer accumulate (exact).

__global__ __launch_bounds__(256) void agg0_kernel(
    const unsigned int* __restrict__ Xb,   // [NN][64] packed bf16 pairs
    const uint2* __restrict__ Nbit,        // [NS*NN] 64 noise bits
    const int* __restrict__ row_ptr, const int* __restrict__ col_idx,
    const float* __restrict__ eps0p,
    unsigned int* __restrict__ z0) {       // [NS*NN][96]
    const int d = blockIdx.x * 2 + (threadIdx.x >> 7);
    const int cc = threadIdx.x & 127;
    const float c = 1.f + eps0p[0];
    const int beg = row_ptr[d], end = row_ptr[d + 1];
    if (cc < 64) {
        const unsigned int* src = Xb + cc;
        unsigned int u = src[(size_t)d * 64];
        float aL = c * bflo(u), aH = c * bfhi(u);
        int e = beg;
        for (; e + 3 < end; e += 4) {
            int i0 = col_idx[e], i1 = col_idx[e + 1], i2 = col_idx[e + 2], i3 = col_idx[e + 3];
            unsigned int u0 = src[(size_t)i0 * 64], u1 = src[(size_t)i1 * 64];
            unsigned int u2 = src[(size_t)i2 * 64], u3 = src[(size_t)i3 * 64];
            aL += (bflo(u0) + bflo(u1)) + (bflo(u2) + bflo(u3));
            aH += (bfhi(u0) + bfhi(u1)) + (bfhi(u2) + bfhi(u3));
        }
        for (; e < end; ++e) {
            unsigned int ue = src[(size_t)col_idx[e] * 64];
            aL += bflo(ue); aH += bfhi(ue);
        }
        unsigned int r = pack2(aL, aH);
        z0[(size_t)d * 96 + cc] = r;             // sample 0
        z0[(size_t)(NN + d) * 96 + cc] = r;      // sample 1 (X part sample-independent)
    } else {
        int j = cc - 64;
        int s = j >> 5, col = j & 31;            // dims 2*col, 2*col+1
        const uint2* src = Nbit + (size_t)s * NN;
        const int word = col >> 4;               // 0 -> .x, 1 -> .y
        const int sh = (2 * col) & 31;
        uint2 uS = src[d];
        unsigned int wS = word ? uS.y : uS.x;
        int c0 = 0, c1 = 0;
        int e = beg;
        for (; e + 3 < end; e += 4) {
            uint2 u0 = src[col_idx[e]], u1 = src[col_idx[e + 1]];
            uint2 u2 = src[col_idx[e + 2]], u3 = src[col_idx[e + 3]];
            unsigned int w0 = word ? u0.y : u0.x, w1 = word ? u1.y : u1.x;
            unsigned int w2 = word ? u2.y : u2.x, w3 = word ? u3.y : u3.x;
            c0 += (int)((w0 >> sh) & 1) + (int)((w1 >> sh) & 1) + (int)((w2 >> sh) & 1) + (int)((w3 >> sh) & 1);
            c1 += (int)((w0 >> (sh + 1)) & 1) + (int)((w1 >> (sh + 1)) & 1) +
                  (int)((w2 >> (sh + 1)) & 1) + (int)((w3 >> (sh + 1)) & 1);
        }
        for (; e < end; ++e) {
            uint2 ue = src[col_idx[e]];
            unsigned int we = word ? ue.y : ue.x;
            c0 += (int)((we >> sh) & 1);
            c1 += (int)((we >> (sh + 1)) & 1);
        }
        float aL = c * (float)((wS >> sh) & 1) + (float)c0;
        float aH = c * (float)((wS >> (sh + 1)) & 1) + (float)c1;
        z0[(size_t)(s * NN + d) * 96 + 64 + col] = pack2(aL, aH);
    }
}

// ---------------- Layer 1 aggregation (bf16 gather, uint2 loads, x8 unroll) ----------------

__global__ __launch_bounds__(256) void agg1_kernel(
    const uint2* __restrict__ h,           // [NS*NN][64] (uint2 = 4 bf16)
    const int* __restrict__ row_ptr, const int* __restrict__ col_idx,
    const float* __restrict__ eps1p,
    uint2* __restrict__ z1) {              // [NS*NN][64]
    const int d = blockIdx.x * 2 + (threadIdx.x >> 7);
    const int s = (threadIdx.x >> 6) & 1;
    const int cc = threadIdx.x & 63;
    const float c = 1.f + eps1p[0];
    const int beg = row_ptr[d], end = row_ptr[d + 1];
    const uint2* src = h + (size_t)s * NN * 64 + cc;
    uint2 u = src[(size_t)d * 64];
    float aL0 = c * bflo(u.x), aH0 = c * bfhi(u.x);
    float aL1 = c * bflo(u.y), aH1 = c * bfhi(u.y);
    int e = beg;
    for (; e + 7 < end; e += 8) {
        uint2 g[8];
#pragma unroll
        for (int q = 0; q < 8; ++q) g[q] = src[(size_t)col_idx[e + q] * 64];
#pragma unroll
        for (int q = 0; q < 8; ++q) {
            aL0 += bflo(g[q].x); aH0 += bfhi(g[q].x);
            aL1 += bflo(g[q].y); aH1 += bfhi(g[q].y);
        }
    }
    for (; e + 3 < end; e += 4) {
        uint2 u0 = src[(size_t)col_idx[e] * 64], u1 = src[(size_t)col_idx[e + 1] * 64];
        uint2 u2 = src[(size_t)col_idx[e + 2] * 64], u3 = src[(size_t)col_idx[e + 3] * 64];
        aL0 += (bflo(u0.x) + bflo(u1.x)) + (bflo(u2.x) + bflo(u3.x));
        aH0 += (bfhi(u0.x) + bfhi(u1.x)) + (bfhi(u2.x) + bfhi(u3.x));
        aL1 += (bflo(u0.y) + bflo(u1.y)) + (bflo(u2.y) + bflo(u3.y));
        aH1 += (bfhi(u0.y) + bfhi(u1.y)) + (bfhi(u2.y) + bfhi(u3.y));
    }
    for (; e < end; ++e) {
        uint2 ue = src[(size_t)col_idx[e] * 64];
        aL0 += bflo(ue.x); aH0 += bfhi(ue.x);
        aL1 += bflo(ue.y); aH1 += bfhi(ue.y);
    }
    uint2 r; r.x = pack2(aL0, aH0); r.y = pack2(aL1, aH1);
    z1[(size_t)(s * NN + d) * 64 + cc] = r;
}

// ---------------- GEMM: C = relu(A @ W + b), N fixed at 256 ----------------
// Each wave: 32 rows (two 16-row tiles sharing each B fragment) x 256 cols.
// Layouts (m89/m120-verified): A[m=lane&15][k=quad*8+j]; B[k=quad*8+j][n=lane&15];
// D: col=lane&15, row=quad*4+reg.

__device__ inline void store_out(float* C, size_t idx, float v) { C[idx] = v; }
__device__ inline void store_out(__hip_bfloat16* C, size_t idx, float v) { C[idx] = __float2bfloat16(v); }

template <typename OUT_T>
__global__ __launch_bounds__(256) void gemm_bias_relu(
    const __hip_bfloat16* __restrict__ A, const __hip_bfloat16* __restrict__ Wt,
    const float* __restrict__ bias, OUT_T* __restrict__ C,
    int M, int K) {
    const int lane = threadIdx.x & 63;
    const int wave = threadIdx.x >> 6;
    const int rowBase = blockIdx.x * 128 + wave * 32;   // M % 32 == 0
    if (rowBase >= M) return;
    const int lo = lane & 15;
    const int quad = lane >> 4;

    floatx4 acc0[16], acc1[16];
#pragma unroll
    for (int t = 0; t < 16; ++t) {
        acc0[t] = (floatx4){0.f, 0.f, 0.f, 0.f};
        acc1[t] = (floatx4){0.f, 0.f, 0.f, 0.f};
    }

    const __hip_bfloat16* arow0 = A + (size_t)(rowBase + lo) * K + quad * 8;
    const __hip_bfloat16* arow1 = arow0 + (size_t)16 * K;
    for (int k0 = 0; k0 < K; k0 += 32) {
        bf16x8 a0 = *reinterpret_cast<const bf16x8*>(arow0 + k0);
        bf16x8 a1 = *reinterpret_cast<const bf16x8*>(arow1 + k0);
#pragma unroll
        for (int t = 0; t < 16; ++t) {
            bf16x8 b = *reinterpret_cast<const bf16x8*>(Wt + (size_t)(t * 16 + lo) * K + k0 + quad * 8);
            acc0[t] = __builtin_amdgcn_mfma_f32_16x16x32_bf16(a0, b, acc0[t], 0, 0, 0);
            acc1[t] = __builtin_amdgcn_mfma_f32_16x16x32_bf16(a1, b, acc1[t], 0, 0, 0);
        }
    }

#pragma unroll
    for (int t = 0; t < 16; ++t) {
        int col = t * 16 + lo;
        float bv = bias[col];
#pragma unroll
        for (int r = 0; r < 4; ++r) {
            int row0 = rowBase + quad * 4 + r;
            float v0 = acc0[t][r] + bv;
            store_out(C, (size_t)row0 * DOUT + col, v0 > 0.f ? v0 : 0.f);
            float v1 = acc1[t][r] + bv;
            store_out(C, (size_t)(row0 + 16) * DOUT + col, v1 > 0.f ? v1 : 0.f);
        }
    }
}

// ---------------- epsilon passthrough (output 1, fp32) ----------------

__global__ void copy_eps(const uint4* __restrict__ src, uint4* __restrict__ dst) {
    int i = blockIdx.x * blockDim.x + threadIdx.x;
    const int n16 = (NS * NN * DNOISE * 4) / 16;
    if (i < n16) dst[i] = src[i];
}

extern "C" void kernel_launch(void* const* d_in, const int* in_sizes, int n_in,
                              void* d_out, int out_size, void* d_ws, size_t ws_size,
                              hipStream_t stream) {
    const float* X = (const float*)d_in[0];
    const float* noise = (const float*)d_in[1];
    const int* esrc = (const int*)d_in[2];
    const int* edst = (const int*)d_in[3];
    const float* W0 = (const float*)d_in[4];
    const float* b0 = (const float*)d_in[5];
    const float* W1 = (const float*)d_in[6];
    const float* b1 = (const float*)d_in[7];
    const float* eps0 = (const float*)d_in[8];
    const float* eps1 = (const float*)d_in[9];
    float* out = (float*)d_out;

    const int M = NS * NN;  // 100000

    // Workspace carve (~56 MB, proven footprint).
    char* w = (char*)d_ws;
    auto carve = [&](size_t bytes) { char* p = w; w += (bytes + 511) & ~(size_t)511; return p; };
    int* cursor = (int*)carve((size_t)NN * 4);
    int* row_ptr = (int*)carve((size_t)(NN + 1) * 4);
    int* col_idx = (int*)carve((size_t)NE * 4);
    int* bsum = (int*)carve((size_t)NB * 4);
    uint2* Nbit = (uint2*)carve((size_t)M * 8);                    // 800 KB, L2-resident
    __hip_bfloat16* Wt0 = (__hip_bfloat16*)carve((size_t)DH0 * DOUT * 2);
    __hip_bfloat16* Wt1 = (__hip_bfloat16*)carve((size_t)DOUT * DOUT * 2);
    unsigned int* z = (unsigned int*)carve((size_t)M * DOUT * 2);  // z0 (96 uints/row) then z1 (64 uint2/row)

    // h1 (bf16, 51.2 MB) staged at the start of the fp32 out region (102.4 MB);
    // dead before gemm1 overwrites that region with out.
    __hip_bfloat16* h1 = (__hip_bfloat16*)d_out;
    // bf16 X copy lives in the epsilon region (25.6 MB); dead after agg0,
    // overwritten by copy_eps at the very end.
    unsigned short* Xb = (unsigned short*)(out + (size_t)M * DOUT);  // 12.8 MB

    hipMemsetAsync(cursor, 0, (size_t)NN * 4, stream);
    count_kernel<<<(NE + 255) / 256, 256, 0, stream>>>(edst, cursor);
    scanA_kernel<<<NB, 1024, 0, stream>>>(cursor, bsum);
    scanB_kernel<<<1, 64, 0, stream>>>(bsum);
    scanC_kernel<<<NB, 1024, 0, stream>>>(cursor, bsum, row_ptr);
    fill_kernel<<<(NE + 255) / 256, 256, 0, stream>>>(esrc, edst, cursor, col_idx);
    prep_kernel<<<XB4 + NR_BLOCKS, 256, 0, stream>>>(X, Xb, noise, Nbit);
    transpose_both<<<2 * DOUT, 256, 0, stream>>>(W0, W1, Wt0, Wt1);

    agg0_kernel<<<NN / 2, 256, 0, stream>>>(
        (const unsigned int*)Xb, Nbit, row_ptr, col_idx, eps0, z);
    gemm_bias_relu<__hip_bfloat16><<<(M + 127) / 128, 256, 0, stream>>>(
        (const __hip_bfloat16*)z, Wt0, b0, h1, M, DH0);
    agg1_kernel<<<NN / 2, 256, 0, stream>>>(
        (const uint2*)h1, row_ptr, col_idx, eps1, (uint2*)z);
    gemm_bias_relu<float><<<(M + 127) / 128, 256, 0, stream>>>(
        (const __hip_bfloat16*)z, Wt1, b1, out, M, DOUT);

    copy_eps<<<((NS * NN * DNOISE * 4 / 16) + 255) / 256, 256, 0, stream>>>(
        (const uint4*)noise, (uint4*)(out + (size_t)M * DOUT));
}